// Round 3
// baseline (13339.005 us; speedup 1.0000x reference)
//
#include <hip/hip_runtime.h>
#include <hip/hip_bf16.h>

typedef __attribute__((ext_vector_type(4))) float fx4;
typedef __attribute__((ext_vector_type(8))) short bf8;   // 8 x bf16
typedef __attribute__((ext_vector_type(4))) short sx4;   // 4 x bf16

#define LNB 32   // persistent blocks in recurrence kernel

__device__ __forceinline__ short f2bf(float f) {
  __hip_bfloat16 h = __float2bfloat16(f);
  return *reinterpret_cast<short*>(&h);
}
__device__ __forceinline__ float bf2f(short s) {
  union { unsigned u; float f; } c; c.u = ((unsigned)(unsigned short)s) << 16; return c.f;
}
__device__ __forceinline__ float rcpf(float x) { return __builtin_amdgcn_rcpf(x); }

__device__ __forceinline__ void gld16(const void* g, void* l) {
  __builtin_amdgcn_global_load_lds(
      (const __attribute__((address_space(1))) unsigned int*)g,
      (__attribute__((address_space(3))) unsigned int*)l, 16, 0, 0);
}

// x (B=32,T=512,D=256) fp32 -> xt (T,B,256) bf16 hi+lo (rows = t*32+b)
__global__ __launch_bounds__(256) void conv_x_k(const float* __restrict__ x,
                                                short* __restrict__ xhi, short* __restrict__ xlo) {
  int i = blockIdx.x * 256 + threadIdx.x;
  fx4 v = *(const fx4*)(x + (size_t)i * 4);
  int k = (i * 4) & 255;
  int row = (i * 4) >> 8;                            // b*512 + t
  int b = row >> 9, t = row & 511;
  sx4 hi, lo;
#pragma unroll
  for (int e = 0; e < 4; ++e) {
    hi[e] = f2bf(v[e]);
    lo[e] = f2bf(v[e] - bf2f(hi[e]));
  }
  size_t o = ((size_t)(t * 32 + b)) * 256 + k;
  *(sx4*)(xhi + o) = hi;
  *(sx4*)(xlo + o) = lo;
}

// fp32 weights -> bf16 hi+lo
__global__ __launch_bounds__(256) void conv_w_k(const float* __restrict__ s,
                                                short* __restrict__ dh, short* __restrict__ dl, int n4) {
  int i = blockIdx.x * 256 + threadIdx.x;
  if (i < n4) {
    fx4 v = *(const fx4*)(s + (size_t)i * 4);
    sx4 hi, lo;
#pragma unroll
    for (int e = 0; e < 4; ++e) {
      hi[e] = f2bf(v[e]);
      lo[e] = f2bf(v[e] - bf2f(hi[e]));
    }
    *(sx4*)(dh + (size_t)i * 4) = hi;
    *(sx4*)(dl + (size_t)i * 4) = lo;
  }
}

// C[M=16384][1536] = (Ahi+Alo)[M][K] * (Whi+Wlo)[1536][K]^T + bias (fp32 out)
// 128x128 tile, BK=64, 4 waves, global_load_lds staging, XOR-swizzled LDS.
__global__ __launch_bounds__(256) void gemm_in(
    const short* __restrict__ Ahi, const short* __restrict__ Alo,
    const short* __restrict__ Whi, const short* __restrict__ Wlo,
    const float* __restrict__ bias,
    float* __restrict__ C, int K)
{
  __shared__ __align__(16) short Ash[128 * 64];
  __shared__ __align__(16) short Asl[128 * 64];
  __shared__ __align__(16) short Bsh[128 * 64];
  __shared__ __align__(16) short Bsl[128 * 64];
  const int tid = threadIdx.x;
  const int w = tid >> 6, l = tid & 63;
  const int lm = l & 15, lk = l >> 4;
  const int bm = blockIdx.x / 12, bn = blockIdx.x % 12;
  const int r0 = bm * 128, n0 = bn * 128;
  const int mb = (w & 1) * 64, nb = (w >> 1) * 64;

  fx4 acc[4][4];
#pragma unroll
  for (int i = 0; i < 4; ++i)
#pragma unroll
    for (int j = 0; j < 4; ++j) acc[i][j] = (fx4){0.f, 0.f, 0.f, 0.f};

  const int kIter = K >> 6;
  for (int kt = 0; kt < kIter; ++kt) {
    const int k0 = kt * 64;
    __syncthreads();
#pragma unroll
    for (int it = 0; it < 4; ++it) {
      const int cbase = it * 256 + w * 64;
      const int c = cbase + l;
      const int r = c >> 3;
      const int c8 = (c & 7) ^ (r & 7);
      const size_t go = (size_t)(r0 + r) * K + k0 + c8 * 8;
      const size_t gw = (size_t)(n0 + r) * K + k0 + c8 * 8;
      gld16(Ahi + go, (char*)Ash + cbase * 16);
      gld16(Alo + go, (char*)Asl + cbase * 16);
      gld16(Whi + gw, (char*)Bsh + cbase * 16);
      gld16(Wlo + gw, (char*)Bsl + cbase * 16);
    }
    asm volatile("s_waitcnt vmcnt(0)" ::: "memory");
    __syncthreads();
#pragma unroll
    for (int kk = 0; kk < 2; ++kk) {
      bf8 ah[4], al[4], bh[4], bl[4];
#pragma unroll
      for (int i = 0; i < 4; ++i) {
        const int row = mb + i * 16 + lm;
        const int off = row * 64 + (((kk * 4 + lk) ^ (row & 7)) * 8);
        ah[i] = *(const bf8*)(Ash + off);
        al[i] = *(const bf8*)(Asl + off);
      }
#pragma unroll
      for (int j = 0; j < 4; ++j) {
        const int row = nb + j * 16 + lm;
        const int off = row * 64 + (((kk * 4 + lk) ^ (row & 7)) * 8);
        bh[j] = *(const bf8*)(Bsh + off);
        bl[j] = *(const bf8*)(Bsl + off);
      }
#pragma unroll
      for (int i = 0; i < 4; ++i)
#pragma unroll
        for (int j = 0; j < 4; ++j) {
          acc[i][j] = __builtin_amdgcn_mfma_f32_16x16x32_bf16(ah[i], bh[j], acc[i][j], 0, 0, 0);
          acc[i][j] = __builtin_amdgcn_mfma_f32_16x16x32_bf16(al[i], bh[j], acc[i][j], 0, 0, 0);
          acc[i][j] = __builtin_amdgcn_mfma_f32_16x16x32_bf16(ah[i], bl[j], acc[i][j], 0, 0, 0);
        }
    }
  }

#pragma unroll
  for (int j = 0; j < 4; ++j) {
    const int col = n0 + nb + j * 16 + lm;
    const float bv = bias[col];
#pragma unroll
    for (int i = 0; i < 4; ++i) {
      const int R = r0 + mb + i * 16 + lk * 4;
#pragma unroll
      for (int q = 0; q < 4; ++q)
        C[(size_t)(R + q) * 1536 + col] = acc[i][j][q] + bv;
    }
  }
}

// flag-based all-to-all barrier across the LNB persistent blocks
__device__ __forceinline__ void gridbar(int* flags, int target) {
  __threadfence();
  __syncthreads();
  if (threadIdx.x == 0)
    __hip_atomic_store(flags + blockIdx.x * 32, target, __ATOMIC_RELEASE, __HIP_MEMORY_SCOPE_AGENT);
  if (threadIdx.x < LNB) {
    while (__hip_atomic_load(flags + threadIdx.x * 32, __ATOMIC_ACQUIRE, __HIP_MEMORY_SCOPE_AGENT) < target) {}
  }
  __syncthreads();
  __threadfence();
}

// Persistent per-layer recurrence. 32 blocks x 256 thr. Block p owns 16 output
// cols j0=p*16, i.e. Wh rows {j0..j0+15, 512+j0.., 1024+j0..} (48 rows).
// Waves: (w>>1)=M-half of batch, (w&1)=K-half. Wh hi+lo in registers
// (48 frags = 192 VGPR). h broadcast via global bf16 hi+lo double buffer.
// hg layout: [dbuf 2][hi/lo 2][32][512] bf16.
__global__ __launch_bounds__(256, 1) void rec_layer(
    const float* __restrict__ A,      // [512*32][1536] fp32 = xin@Wi.T + bi
    const float* __restrict__ Wh,     // [1536][512] fp32
    const float* __restrict__ bh,     // [1536]
    short* __restrict__ Hhi,          // [512*32][512] bf16
    short* __restrict__ Hlo,
    short* __restrict__ hg,
    int* flags,
    float* __restrict__ out,          // null or [32][512] fp32
    int genBase, int writeOut)
{
  __shared__ __align__(16) float m_lds[2][32][52];  // [K-half][batch][48 rows pad 52]
  __shared__ float bhs[48];
  const int tid = threadIdx.x;
  const int w = tid >> 6, l = tid & 63;
  const int lm = l & 15, lk = l >> 4;
  const int j0 = blockIdx.x * 16;
  const int mbase = (w >> 1) * 16;
  const int kbase = (w & 1) * 256;
  const int kp = w & 1;

  // ---- Wh slice -> register B-fragments, hi+lo ----
  bf8 bwh[3][8], bwl[3][8];
#pragma unroll
  for (int ntl = 0; ntl < 3; ++ntl) {
    const int grow = ntl * 512 + j0 + lm;
#pragma unroll
    for (int ks = 0; ks < 8; ++ks) {
      const float* src = Wh + (size_t)grow * 512 + kbase + ks * 32 + lk * 8;
      fx4 f0 = *(const fx4*)(src);
      fx4 f1 = *(const fx4*)(src + 4);
      bf8 vh, vl;
#pragma unroll
      for (int e = 0; e < 4; ++e) {
        vh[e] = f2bf(f0[e]); vl[e] = f2bf(f0[e] - bf2f(vh[e]));
        vh[4 + e] = f2bf(f1[e]); vl[4 + e] = f2bf(f1[e] - bf2f(vh[4 + e]));
      }
      bwh[ntl][ks] = vh; bwl[ntl][ks] = vl;
    }
  }
  if (tid < 48) bhs[tid] = bh[(tid >> 4) * 512 + j0 + (tid & 15)];
  {  // zero own slice of h dbuf0 (hi and lo)
    const int b = tid >> 3, c2 = (tid & 7) * 2;
    *(int*)(hg + (size_t)b * 512 + j0 + c2) = 0;
    *(int*)(hg + (size_t)32 * 512 + (size_t)b * 512 + j0 + c2) = 0;
  }
  gridbar(flags, genBase + 1);

  const int cb = tid >> 3, c2 = (tid & 7) * 2;   // cell phase: (batch, 2 cols)
  float hv0 = 0.f, hv1 = 0.f;                    // fp32 running h (own 2 cols)

  for (int t = 0; t < 512; ++t) {
    const int rb = t & 1, wb = rb ^ 1;
    // prefetch A for this step
    const float* Arow = A + (size_t)(t * 32 + cb) * 1536 + j0 + c2;
    float ar0 = Arow[0],    ar1 = Arow[1];
    float az0 = Arow[512],  az1 = Arow[513];
    float an0 = Arow[1024], an1 = Arow[1025];

    // h2h = (hh+hl) @ (Wh_hi+Wh_lo)^T  via 3-term MFMA
    const short* hrh = hg + (size_t)(rb * 2 + 0) * (32 * 512);
    const short* hrl = hg + (size_t)(rb * 2 + 1) * (32 * 512);
    fx4 acc[3];
    acc[0] = acc[1] = acc[2] = (fx4){0.f, 0.f, 0.f, 0.f};
#pragma unroll
    for (int ks = 0; ks < 8; ++ks) {
      const size_t o = (size_t)(mbase + lm) * 512 + kbase + ks * 32 + lk * 8;
      bf8 ah = *(const bf8*)(hrh + o);
      bf8 al = *(const bf8*)(hrl + o);
#pragma unroll
      for (int ntl = 0; ntl < 3; ++ntl) {
        acc[ntl] = __builtin_amdgcn_mfma_f32_16x16x32_bf16(ah, bwh[ntl][ks], acc[ntl], 0, 0, 0);
        acc[ntl] = __builtin_amdgcn_mfma_f32_16x16x32_bf16(al, bwh[ntl][ks], acc[ntl], 0, 0, 0);
        acc[ntl] = __builtin_amdgcn_mfma_f32_16x16x32_bf16(ah, bwl[ntl][ks], acc[ntl], 0, 0, 0);
      }
    }
#pragma unroll
    for (int ntl = 0; ntl < 3; ++ntl)
#pragma unroll
      for (int q = 0; q < 4; ++q)
        m_lds[kp][mbase + lk * 4 + q][ntl * 16 + lm] = acc[ntl][q];
    __syncthreads();

    float m_r0 = m_lds[0][cb][c2]      + m_lds[1][cb][c2];
    float m_r1 = m_lds[0][cb][c2 + 1]  + m_lds[1][cb][c2 + 1];
    float m_z0 = m_lds[0][cb][16 + c2]     + m_lds[1][cb][16 + c2];
    float m_z1 = m_lds[0][cb][16 + c2 + 1] + m_lds[1][cb][16 + c2 + 1];
    float m_n0 = m_lds[0][cb][32 + c2]     + m_lds[1][cb][32 + c2];
    float m_n1 = m_lds[0][cb][32 + c2 + 1] + m_lds[1][cb][32 + c2 + 1];

    float hn[2], hvv[2] = {hv0, hv1};
    float mrv[2] = {m_r0, m_r1}, mzv[2] = {m_z0, m_z1}, mnv[2] = {m_n0, m_n1};
    float arv[2] = {ar0, ar1}, azv[2] = {az0, az1}, anv[2] = {an0, an1};
#pragma unroll
    for (int e = 0; e < 2; ++e) {
      const int c = c2 + e;
      float h2r = mrv[e] + bhs[c];
      float h2z = mzv[e] + bhs[16 + c];
      float h2n = mnv[e] + bhs[32 + c];
      float pr = arv[e] + h2r;
      float pz = azv[e] + h2z;
      float pn = anv[e] + h2n;
      float sr = rcpf(1.f + __expf(-pr));  // sigmoid
      float rr = __expf(-__expf(-sr));     // Gumbel squash
      float sz = rcpf(1.f + __expf(-pz));
      float zz = __expf(-__expf(-sz));
      float na = pn + rr * h2n;
      float ex = __expf(2.f * na);         // tanh via exp
      float nn = 1.f - 2.f * rcpf(ex + 1.f);
      hn[e] = (1.f - zz) * nn + zz * hvv[e];
    }
    hv0 = hn[0]; hv1 = hn[1];
    short h0h = f2bf(hn[0]), h0l = f2bf(hn[0] - bf2f(h0h));
    short h1h = f2bf(hn[1]), h1l = f2bf(hn[1] - bf2f(h1h));
    int packh = (int)(unsigned short)h0h | ((int)(unsigned short)h1h << 16);
    int packl = (int)(unsigned short)h0l | ((int)(unsigned short)h1l << 16);
    short* hw = hg + (size_t)(wb * 2) * (32 * 512);
    *(int*)(hw + (size_t)cb * 512 + j0 + c2) = packh;
    *(int*)(hw + (size_t)32 * 512 + (size_t)cb * 512 + j0 + c2) = packl;
    const size_t ho = (size_t)(t * 32 + cb) * 512 + j0 + c2;
    *(int*)(Hhi + ho) = packh;
    *(int*)(Hlo + ho) = packl;
    if (writeOut && t == 511) {
      out[(size_t)cb * 512 + j0 + c2] = hn[0];
      out[(size_t)cb * 512 + j0 + c2 + 1] = hn[1];
    }

    gridbar(flags, genBase + 2 + t);
  }
}

extern "C" void kernel_launch(void* const* d_in, const int* in_sizes, int n_in,
                              void* d_out, int out_size, void* d_ws, size_t ws_size,
                              hipStream_t stream) {
  const float* x   = (const float*)d_in[0];
  const float* Wi0 = (const float*)d_in[1];
  const float* bi0 = (const float*)d_in[2];
  const float* Wh0 = (const float*)d_in[3];
  const float* bh0 = (const float*)d_in[4];
  const float* Wi1 = (const float*)d_in[5];
  const float* bi1 = (const float*)d_in[6];
  const float* Wh1 = (const float*)d_in[7];
  const float* bh1 = (const float*)d_in[8];
  const float* Wi2 = (const float*)d_in[9];
  const float* bi2 = (const float*)d_in[10];
  const float* Wh2 = (const float*)d_in[11];
  const float* bh2 = (const float*)d_in[12];
  float* out = (float*)d_out;
  (void)in_sizes; (void)n_in; (void)out_size; (void)ws_size;

  char* ws = (char*)d_ws;
  size_t off = 0;
  auto alloc = [&](size_t b) { char* p = ws + off; off = (off + b + 255) & ~(size_t)255; return p; };
  float* A      = (float*)alloc(16384ull * 1536 * 4);   // 100.7 MB
  short* xth    = (short*)alloc(16384ull * 256 * 2);
  short* xtl    = (short*)alloc(16384ull * 256 * 2);
  short* Wib0h  = (short*)alloc(1536ull * 256 * 2);
  short* Wib0l  = (short*)alloc(1536ull * 256 * 2);
  short* Wib1h  = (short*)alloc(1536ull * 512 * 2);
  short* Wib1l  = (short*)alloc(1536ull * 512 * 2);
  short* Wib2h  = (short*)alloc(1536ull * 512 * 2);
  short* Wib2l  = (short*)alloc(1536ull * 512 * 2);
  short* Hb0h   = (short*)alloc(16384ull * 512 * 2);    // 16.8 MB each
  short* Hb0l   = (short*)alloc(16384ull * 512 * 2);
  short* Hb1h   = (short*)alloc(16384ull * 512 * 2);
  short* Hb1l   = (short*)alloc(16384ull * 512 * 2);
  short* hg     = (short*)alloc(4ull * 32 * 512 * 2);   // [dbuf2][hi/lo2][32][512]
  int*   flags  = (int*)alloc(LNB * 32 * 4);

  hipMemsetAsync(flags, 0, LNB * 32 * 4, stream);
  hipLaunchKernelGGL(conv_x_k, dim3(4096), dim3(256), 0, stream, x, xth, xtl);
  hipLaunchKernelGGL(conv_w_k, dim3(384), dim3(256), 0, stream, Wi0, Wib0h, Wib0l, 98304);
  hipLaunchKernelGGL(conv_w_k, dim3(768), dim3(256), 0, stream, Wi1, Wib1h, Wib1l, 196608);
  hipLaunchKernelGGL(conv_w_k, dim3(768), dim3(256), 0, stream, Wi2, Wib2h, Wib2l, 196608);

  // layer 0
  hipLaunchKernelGGL(gemm_in, dim3(1536), dim3(256), 0, stream, xth, xtl, Wib0h, Wib0l, bi0, A, 256);
  hipLaunchKernelGGL(rec_layer, dim3(LNB), dim3(256), 0, stream, A, Wh0, bh0, Hb0h, Hb0l, hg, flags, (float*)nullptr, 0, 0);
  // layer 1
  hipLaunchKernelGGL(gemm_in, dim3(1536), dim3(256), 0, stream, Hb0h, Hb0l, Wib1h, Wib1l, bi1, A, 512);
  hipLaunchKernelGGL(rec_layer, dim3(LNB), dim3(256), 0, stream, A, Wh1, bh1, Hb1h, Hb1l, hg, flags, (float*)nullptr, 520, 0);
  // layer 2
  hipLaunchKernelGGL(gemm_in, dim3(1536), dim3(256), 0, stream, Hb1h, Hb1l, Wib2h, Wib2l, bi2, A, 512);
  hipLaunchKernelGGL(rec_layer, dim3(LNB), dim3(256), 0, stream, A, Wh2, bh2, Hb0h, Hb0l, hg, flags, out, 1040, 1);
}

// Round 4
// 5944.192 us; speedup vs baseline: 2.2440x; 2.2440x over previous
//
#include <hip/hip_runtime.h>
#include <hip/hip_bf16.h>

typedef __attribute__((ext_vector_type(4))) float fx4;
typedef __attribute__((ext_vector_type(2))) float fx2;
typedef __attribute__((ext_vector_type(8))) short bf8;   // 8 x bf16
typedef __attribute__((ext_vector_type(4))) short sx4;   // 4 x bf16
typedef __attribute__((ext_vector_type(4))) int ix4;

#define LNB 32   // persistent blocks in recurrence kernel

__device__ __forceinline__ short f2bf(float f) {
  __hip_bfloat16 h = __float2bfloat16(f);
  return *reinterpret_cast<short*>(&h);
}
__device__ __forceinline__ float bf2f(short s) {
  union { unsigned u; float f; } c; c.u = ((unsigned)(unsigned short)s) << 16; return c.f;
}
__device__ __forceinline__ float rcpf(float x) { return __builtin_amdgcn_rcpf(x); }
__device__ __forceinline__ bf8 asbf8(ix4 v) { union { ix4 i; bf8 b; } u; u.i = v; return u.b; }

__device__ __forceinline__ void gld16(const void* g, void* l) {
  __builtin_amdgcn_global_load_lds(
      (const __attribute__((address_space(1))) unsigned int*)g,
      (__attribute__((address_space(3))) unsigned int*)l, 16, 0, 0);
}

// coherent (LLC) 16B load, bypasses local L1/L2 — for cross-XCD h broadcast
#define LDCC(dst, p, OFF) \
  asm volatile("global_load_dwordx4 %0, %1, off offset:" OFF " sc0 sc1" \
               : "=v"(dst) : "v"(p) : "memory")
// plain 8B load issued early (latency hidden under barrier wait)
#define LDA8(dst, p, OFF) \
  asm volatile("global_load_dwordx2 %0, %1, off offset:" OFF \
               : "=v"(dst) : "v"(p) : "memory")

// x (B=32,T=512,D=256) fp32 -> xt (T,B,256) bf16 hi+lo (rows = t*32+b)
__global__ __launch_bounds__(256) void conv_x_k(const float* __restrict__ x,
                                                short* __restrict__ xhi, short* __restrict__ xlo) {
  int i = blockIdx.x * 256 + threadIdx.x;
  fx4 v = *(const fx4*)(x + (size_t)i * 4);
  int k = (i * 4) & 255;
  int row = (i * 4) >> 8;                            // b*512 + t
  int b = row >> 9, t = row & 511;
  sx4 hi, lo;
#pragma unroll
  for (int e = 0; e < 4; ++e) {
    hi[e] = f2bf(v[e]);
    lo[e] = f2bf(v[e] - bf2f(hi[e]));
  }
  size_t o = ((size_t)(t * 32 + b)) * 256 + k;
  *(sx4*)(xhi + o) = hi;
  *(sx4*)(xlo + o) = lo;
}

// fp32 weights -> bf16 hi+lo
__global__ __launch_bounds__(256) void conv_w_k(const float* __restrict__ s,
                                                short* __restrict__ dh, short* __restrict__ dl, int n4) {
  int i = blockIdx.x * 256 + threadIdx.x;
  if (i < n4) {
    fx4 v = *(const fx4*)(s + (size_t)i * 4);
    sx4 hi, lo;
#pragma unroll
    for (int e = 0; e < 4; ++e) {
      hi[e] = f2bf(v[e]);
      lo[e] = f2bf(v[e] - bf2f(hi[e]));
    }
    *(sx4*)(dh + (size_t)i * 4) = hi;
    *(sx4*)(dl + (size_t)i * 4) = lo;
  }
}

// C[M=16384][1536] = (Ahi+Alo)[M][K] * (Whi+Wlo)[1536][K]^T + bias (fp32 out)
__global__ __launch_bounds__(256) void gemm_in(
    const short* __restrict__ Ahi, const short* __restrict__ Alo,
    const short* __restrict__ Whi, const short* __restrict__ Wlo,
    const float* __restrict__ bias,
    float* __restrict__ C, int K)
{
  __shared__ __align__(16) short Ash[128 * 64];
  __shared__ __align__(16) short Asl[128 * 64];
  __shared__ __align__(16) short Bsh[128 * 64];
  __shared__ __align__(16) short Bsl[128 * 64];
  const int tid = threadIdx.x;
  const int w = tid >> 6, l = tid & 63;
  const int lm = l & 15, lk = l >> 4;
  const int bm = blockIdx.x / 12, bn = blockIdx.x % 12;
  const int r0 = bm * 128, n0 = bn * 128;
  const int mb = (w & 1) * 64, nb = (w >> 1) * 64;

  fx4 acc[4][4];
#pragma unroll
  for (int i = 0; i < 4; ++i)
#pragma unroll
    for (int j = 0; j < 4; ++j) acc[i][j] = (fx4){0.f, 0.f, 0.f, 0.f};

  const int kIter = K >> 6;
  for (int kt = 0; kt < kIter; ++kt) {
    const int k0 = kt * 64;
    __syncthreads();
#pragma unroll
    for (int it = 0; it < 4; ++it) {
      const int cbase = it * 256 + w * 64;
      const int c = cbase + l;
      const int r = c >> 3;
      const int c8 = (c & 7) ^ (r & 7);
      const size_t go = (size_t)(r0 + r) * K + k0 + c8 * 8;
      const size_t gw = (size_t)(n0 + r) * K + k0 + c8 * 8;
      gld16(Ahi + go, (char*)Ash + cbase * 16);
      gld16(Alo + go, (char*)Asl + cbase * 16);
      gld16(Whi + gw, (char*)Bsh + cbase * 16);
      gld16(Wlo + gw, (char*)Bsl + cbase * 16);
    }
    asm volatile("s_waitcnt vmcnt(0)" ::: "memory");
    __syncthreads();
#pragma unroll
    for (int kk = 0; kk < 2; ++kk) {
      bf8 ah[4], al[4], bh[4], bl[4];
#pragma unroll
      for (int i = 0; i < 4; ++i) {
        const int row = mb + i * 16 + lm;
        const int off = row * 64 + (((kk * 4 + lk) ^ (row & 7)) * 8);
        ah[i] = *(const bf8*)(Ash + off);
        al[i] = *(const bf8*)(Asl + off);
      }
#pragma unroll
      for (int j = 0; j < 4; ++j) {
        const int row = nb + j * 16 + lm;
        const int off = row * 64 + (((kk * 4 + lk) ^ (row & 7)) * 8);
        bh[j] = *(const bf8*)(Bsh + off);
        bl[j] = *(const bf8*)(Bsl + off);
      }
#pragma unroll
      for (int i = 0; i < 4; ++i)
#pragma unroll
        for (int j = 0; j < 4; ++j) {
          acc[i][j] = __builtin_amdgcn_mfma_f32_16x16x32_bf16(ah[i], bh[j], acc[i][j], 0, 0, 0);
          acc[i][j] = __builtin_amdgcn_mfma_f32_16x16x32_bf16(al[i], bh[j], acc[i][j], 0, 0, 0);
          acc[i][j] = __builtin_amdgcn_mfma_f32_16x16x32_bf16(ah[i], bl[j], acc[i][j], 0, 0, 0);
        }
    }
  }

#pragma unroll
  for (int j = 0; j < 4; ++j) {
    const int col = n0 + nb + j * 16 + lm;
    const float bv = bias[col];
#pragma unroll
    for (int i = 0; i < 4; ++i) {
      const int R = r0 + mb + i * 16 + lk * 4;
#pragma unroll
      for (int q = 0; q < 4; ++q)
        C[(size_t)(R + q) * 1536 + col] = acc[i][j][q] + bv;
    }
  }
}

// Persistent per-layer recurrence. 32 blocks x 256 thr. Block p owns 16 output
// cols j0=p*16 (Wh rows {j0.., 512+j0.., 1024+j0..}, hi+lo in registers).
// h broadcast via LLC: RELAXED agent atomics + sc0sc1 loads — NO threadfence,
// NO acquire/release (avoids buffer_wbl2/buffer_inv, the R2 8.6us/step cost).
// hg layout: [dbuf 2][hi/lo 2][32][512] bf16.
__global__ __launch_bounds__(256, 1) void rec_layer(
    const float* __restrict__ A,      // [512*32][1536] fp32 = xin@Wi.T + bi
    const float* __restrict__ Wh,     // [1536][512] fp32
    const float* __restrict__ bh,     // [1536]
    short* __restrict__ Hhi,          // [512*32][512] bf16
    short* __restrict__ Hlo,
    short* __restrict__ hg,
    int* flags,
    float* __restrict__ out,          // null or [32][512] fp32
    int genBase, int writeOut)
{
  __shared__ __align__(16) float m_lds[2][32][52];  // [K-half][batch][48 rows pad 52]
  __shared__ float bhs[48];
  const int tid = threadIdx.x;
  const int w = tid >> 6, l = tid & 63;
  const int lm = l & 15, lk = l >> 4;
  const int j0 = blockIdx.x * 16;
  const int mbase = (w >> 1) * 16;
  const int kbase = (w & 1) * 256;
  const int kp = w & 1;

  // ---- Wh slice -> register B-fragments, hi+lo ----
  bf8 bwh[3][8], bwl[3][8];
#pragma unroll
  for (int ntl = 0; ntl < 3; ++ntl) {
    const int grow = ntl * 512 + j0 + lm;
#pragma unroll
    for (int ks = 0; ks < 8; ++ks) {
      const float* src = Wh + (size_t)grow * 512 + kbase + ks * 32 + lk * 8;
      fx4 f0 = *(const fx4*)(src);
      fx4 f1 = *(const fx4*)(src + 4);
      bf8 vh, vl;
#pragma unroll
      for (int e = 0; e < 4; ++e) {
        vh[e] = f2bf(f0[e]); vl[e] = f2bf(f0[e] - bf2f(vh[e]));
        vh[4 + e] = f2bf(f1[e]); vl[4 + e] = f2bf(f1[e] - bf2f(vh[4 + e]));
      }
      bwh[ntl][ks] = vh; bwl[ntl][ks] = vl;
    }
  }
  if (tid < 48) bhs[tid] = bh[(tid >> 4) * 512 + j0 + (tid & 15)];
  {  // zero own slice of h dbuf0 (hi and lo) at the coherence point
    const int b = tid >> 3, zc = (tid & 7) * 2;
    __hip_atomic_store((int*)(hg + (size_t)b * 512 + j0 + zc), 0,
                       __ATOMIC_RELAXED, __HIP_MEMORY_SCOPE_AGENT);
    __hip_atomic_store((int*)(hg + (size_t)32 * 512 + (size_t)b * 512 + j0 + zc), 0,
                       __ATOMIC_RELAXED, __HIP_MEMORY_SCOPE_AGENT);
  }
  __syncthreads();   // drains the stores (vmcnt(0) before s_barrier)
  if (tid == 0)
    __hip_atomic_store(flags + blockIdx.x * 32, genBase + 1,
                       __ATOMIC_RELAXED, __HIP_MEMORY_SCOPE_AGENT);

  const int cb = tid >> 3, c2 = (tid & 7) * 2;   // cell phase: (batch, 2 cols)
  float hv0 = 0.f, hv1 = 0.f;                    // fp32 running h (own 2 cols)

  const short* ph_base = hg + (size_t)(mbase + lm) * 512 + kbase + lk * 8;

  for (int t = 0; t < 512; ++t) {
    const int rb = t & 1, wb = rb ^ 1;

    // issue A loads early — latency hides under the barrier wait
    const float* Arow = A + (size_t)(t * 32 + cb) * 1536 + j0 + c2 + 512;
    fx2 a_r, a_z, a_n;
    LDA8(a_r, Arow, "-2048");
    LDA8(a_z, Arow, "0");
    LDA8(a_n, Arow, "2048");

    // wait until every block has published h_t
    const int target = genBase + 1 + t;
    if (tid < LNB) {
      while (__hip_atomic_load(flags + tid * 32, __ATOMIC_RELAXED,
                               __HIP_MEMORY_SCOPE_AGENT) < target) {}
    }
    __syncthreads();

    // h_t (hi+lo) from LLC, bypassing stale local caches
    const short* ph = ph_base + (size_t)(rb * 2 + 0) * (32 * 512);
    const short* pl = ph_base + (size_t)(rb * 2 + 1) * (32 * 512);
    ix4 rh[8], rl[8];
    LDCC(rh[0], ph, "0");   LDCC(rh[1], ph, "64");  LDCC(rh[2], ph, "128"); LDCC(rh[3], ph, "192");
    LDCC(rh[4], ph, "256"); LDCC(rh[5], ph, "320"); LDCC(rh[6], ph, "384"); LDCC(rh[7], ph, "448");
    LDCC(rl[0], pl, "0");   LDCC(rl[1], pl, "64");  LDCC(rl[2], pl, "128"); LDCC(rl[3], pl, "192");
    LDCC(rl[4], pl, "256"); LDCC(rl[5], pl, "320"); LDCC(rl[6], pl, "384"); LDCC(rl[7], pl, "448");
    asm volatile("s_waitcnt vmcnt(0)" ::: "memory");
    __builtin_amdgcn_sched_barrier(0);     // rule #18: keep MFMA below the wait

    fx4 acc[3];
    acc[0] = acc[1] = acc[2] = (fx4){0.f, 0.f, 0.f, 0.f};
#pragma unroll
    for (int ks = 0; ks < 8; ++ks) {
      bf8 ah = asbf8(rh[ks]);
      bf8 al = asbf8(rl[ks]);
#pragma unroll
      for (int ntl = 0; ntl < 3; ++ntl) {
        acc[ntl] = __builtin_amdgcn_mfma_f32_16x16x32_bf16(ah, bwh[ntl][ks], acc[ntl], 0, 0, 0);
        acc[ntl] = __builtin_amdgcn_mfma_f32_16x16x32_bf16(al, bwh[ntl][ks], acc[ntl], 0, 0, 0);
        acc[ntl] = __builtin_amdgcn_mfma_f32_16x16x32_bf16(ah, bwl[ntl][ks], acc[ntl], 0, 0, 0);
      }
    }
#pragma unroll
    for (int ntl = 0; ntl < 3; ++ntl)
#pragma unroll
      for (int q = 0; q < 4; ++q)
        m_lds[kp][mbase + lk * 4 + q][ntl * 16 + lm] = acc[ntl][q];
    __syncthreads();

    float mrv[2], mzv[2], mnv[2];
#pragma unroll
    for (int e = 0; e < 2; ++e) {
      mrv[e] = m_lds[0][cb][c2 + e]      + m_lds[1][cb][c2 + e];
      mzv[e] = m_lds[0][cb][16 + c2 + e] + m_lds[1][cb][16 + c2 + e];
      mnv[e] = m_lds[0][cb][32 + c2 + e] + m_lds[1][cb][32 + c2 + e];
    }
    float arv[2] = {a_r[0], a_r[1]}, azv[2] = {a_z[0], a_z[1]}, anv[2] = {a_n[0], a_n[1]};
    float hvv[2] = {hv0, hv1}, hn[2];
#pragma unroll
    for (int e = 0; e < 2; ++e) {
      const int c = c2 + e;
      float h2r = mrv[e] + bhs[c];
      float h2z = mzv[e] + bhs[16 + c];
      float h2n = mnv[e] + bhs[32 + c];
      float pr = arv[e] + h2r;
      float pz = azv[e] + h2z;
      float pn = anv[e] + h2n;
      float sr = rcpf(1.f + __expf(-pr));  // sigmoid
      float rr = __expf(-__expf(-sr));     // Gumbel squash
      float sz = rcpf(1.f + __expf(-pz));
      float zz = __expf(-__expf(-sz));
      float na = pn + rr * h2n;
      float ex = __expf(2.f * na);         // tanh via exp
      float nn = 1.f - 2.f * rcpf(ex + 1.f);
      hn[e] = (1.f - zz) * nn + zz * hvv[e];
    }
    hv0 = hn[0]; hv1 = hn[1];
    short h0h = f2bf(hn[0]), h0l = f2bf(hn[0] - bf2f(h0h));
    short h1h = f2bf(hn[1]), h1l = f2bf(hn[1] - bf2f(h1h));
    int packh = (int)(unsigned short)h0h | ((int)(unsigned short)h1h << 16);
    int packl = (int)(unsigned short)h0l | ((int)(unsigned short)h1l << 16);

    // publish h_{t+1} to the coherence point
    short* hw = hg + (size_t)(wb * 2) * (32 * 512);
    __hip_atomic_store((int*)(hw + (size_t)cb * 512 + j0 + c2), packh,
                       __ATOMIC_RELAXED, __HIP_MEMORY_SCOPE_AGENT);
    __hip_atomic_store((int*)(hw + (size_t)32 * 512 + (size_t)cb * 512 + j0 + c2), packl,
                       __ATOMIC_RELAXED, __HIP_MEMORY_SCOPE_AGENT);
    __syncthreads();   // vmcnt(0) drain before barrier = release for the block
    if (tid == 0)
      __hip_atomic_store(flags + blockIdx.x * 32, genBase + 2 + t,
                         __ATOMIC_RELAXED, __HIP_MEMORY_SCOPE_AGENT);

    // history / final output — off the critical path
    const size_t ho = (size_t)(t * 32 + cb) * 512 + j0 + c2;
    *(int*)(Hhi + ho) = packh;
    *(int*)(Hlo + ho) = packl;
    if (writeOut && t == 511) {
      out[(size_t)cb * 512 + j0 + c2] = hn[0];
      out[(size_t)cb * 512 + j0 + c2 + 1] = hn[1];
    }
  }
}

extern "C" void kernel_launch(void* const* d_in, const int* in_sizes, int n_in,
                              void* d_out, int out_size, void* d_ws, size_t ws_size,
                              hipStream_t stream) {
  const float* x   = (const float*)d_in[0];
  const float* Wi0 = (const float*)d_in[1];
  const float* bi0 = (const float*)d_in[2];
  const float* Wh0 = (const float*)d_in[3];
  const float* bh0 = (const float*)d_in[4];
  const float* Wi1 = (const float*)d_in[5];
  const float* bi1 = (const float*)d_in[6];
  const float* Wh1 = (const float*)d_in[7];
  const float* bh1 = (const float*)d_in[8];
  const float* Wi2 = (const float*)d_in[9];
  const float* bi2 = (const float*)d_in[10];
  const float* Wh2 = (const float*)d_in[11];
  const float* bh2 = (const float*)d_in[12];
  float* out = (float*)d_out;
  (void)in_sizes; (void)n_in; (void)out_size; (void)ws_size;

  char* ws = (char*)d_ws;
  size_t off = 0;
  auto alloc = [&](size_t b) { char* p = ws + off; off = (off + b + 255) & ~(size_t)255; return p; };
  float* A      = (float*)alloc(16384ull * 1536 * 4);   // 100.7 MB
  short* xth    = (short*)alloc(16384ull * 256 * 2);
  short* xtl    = (short*)alloc(16384ull * 256 * 2);
  short* Wib0h  = (short*)alloc(1536ull * 256 * 2);
  short* Wib0l  = (short*)alloc(1536ull * 256 * 2);
  short* Wib1h  = (short*)alloc(1536ull * 512 * 2);
  short* Wib1l  = (short*)alloc(1536ull * 512 * 2);
  short* Wib2h  = (short*)alloc(1536ull * 512 * 2);
  short* Wib2l  = (short*)alloc(1536ull * 512 * 2);
  short* Hb0h   = (short*)alloc(16384ull * 512 * 2);    // 16.8 MB each
  short* Hb0l   = (short*)alloc(16384ull * 512 * 2);
  short* Hb1h   = (short*)alloc(16384ull * 512 * 2);
  short* Hb1l   = (short*)alloc(16384ull * 512 * 2);
  short* hg     = (short*)alloc(4ull * 32 * 512 * 2);   // [dbuf2][hi/lo2][32][512]
  int*   flags  = (int*)alloc(LNB * 32 * 4);

  hipMemsetAsync(flags, 0, LNB * 32 * 4, stream);
  hipLaunchKernelGGL(conv_x_k, dim3(4096), dim3(256), 0, stream, x, xth, xtl);
  hipLaunchKernelGGL(conv_w_k, dim3(384), dim3(256), 0, stream, Wi0, Wib0h, Wib0l, 98304);
  hipLaunchKernelGGL(conv_w_k, dim3(768), dim3(256), 0, stream, Wi1, Wib1h, Wib1l, 196608);
  hipLaunchKernelGGL(conv_w_k, dim3(768), dim3(256), 0, stream, Wi2, Wib2h, Wib2l, 196608);

  // layer 0
  hipLaunchKernelGGL(gemm_in, dim3(1536), dim3(256), 0, stream, xth, xtl, Wib0h, Wib0l, bi0, A, 256);
  hipLaunchKernelGGL(rec_layer, dim3(LNB), dim3(256), 0, stream, A, Wh0, bh0, Hb0h, Hb0l, hg, flags, (float*)nullptr, 0, 0);
  // layer 1
  hipLaunchKernelGGL(gemm_in, dim3(1536), dim3(256), 0, stream, Hb0h, Hb0l, Wib1h, Wib1l, bi1, A, 512);
  hipLaunchKernelGGL(rec_layer, dim3(LNB), dim3(256), 0, stream, A, Wh1, bh1, Hb1h, Hb1l, hg, flags, (float*)nullptr, 520, 0);
  // layer 2
  hipLaunchKernelGGL(gemm_in, dim3(1536), dim3(256), 0, stream, Hb1h, Hb1l, Wib2h, Wib2l, bi2, A, 512);
  hipLaunchKernelGGL(rec_layer, dim3(LNB), dim3(256), 0, stream, A, Wh2, bh2, Hb0h, Hb0l, hg, flags, out, 1040, 1);
}

// Round 5
// 3339.766 us; speedup vs baseline: 3.9940x; 1.7798x over previous
//
#include <hip/hip_runtime.h>
#include <hip/hip_bf16.h>

typedef __attribute__((ext_vector_type(4))) float fx4;
typedef __attribute__((ext_vector_type(8))) short bf8;   // 8 x bf16
typedef __attribute__((ext_vector_type(4))) short sx4;   // 4 x bf16
typedef __attribute__((ext_vector_type(4))) int ix4;

#define NBLK 96          // 3 layers x 32 blocks
#define HSZ (32 * 512)   // one h plane (batch x hidden) in shorts

__device__ __forceinline__ short f2bf(float f) {
  __hip_bfloat16 h = __float2bfloat16(f);
  return *reinterpret_cast<short*>(&h);
}
__device__ __forceinline__ float bf2f(short s) {
  union { unsigned u; float f; } c; c.u = ((unsigned)(unsigned short)s) << 16; return c.f;
}
__device__ __forceinline__ float rcpf(float x) { return __builtin_amdgcn_rcpf(x); }
__device__ __forceinline__ bf8 asbf8(ix4 v) { union { ix4 i; bf8 b; } u; u.i = v; return u.b; }

// coherent (LLC) 16B load, bypasses local L1/L2 — for cross-XCD h broadcast
#define LDH(dst, p, OFF) \
  asm volatile("global_load_dwordx4 %0, %1, off offset:" OFF " sc0 sc1" \
               : "=v"(dst) : "v"(p) : "memory")
// plain cached 16B load (static data: x)
#define LDP(dst, p, OFF) \
  asm volatile("global_load_dwordx4 %0, %1, off offset:" OFF \
               : "=v"(dst) : "v"(p) : "memory")

#define LDH8(A, P) do { \
  LDH(A[0], P, "0");   LDH(A[1], P, "64");  LDH(A[2], P, "128"); LDH(A[3], P, "192"); \
  LDH(A[4], P, "256"); LDH(A[5], P, "320"); LDH(A[6], P, "384"); LDH(A[7], P, "448"); } while (0)
#define LDP4(A, P) do { \
  LDP(A[0], P, "0");   LDP(A[1], P, "64");  LDP(A[2], P, "128"); LDP(A[3], P, "192"); } while (0)

// x (B=32,T=512,D=256) fp32 -> xt (T,B,256) bf16 hi+lo (rows = t*32+b)
__global__ __launch_bounds__(256) void conv_x_k(const float* __restrict__ x,
                                                short* __restrict__ xhi, short* __restrict__ xlo) {
  int i = blockIdx.x * 256 + threadIdx.x;
  fx4 v = *(const fx4*)(x + (size_t)i * 4);
  int k = (i * 4) & 255;
  int row = (i * 4) >> 8;                            // b*512 + t
  int b = row >> 9, t = row & 511;
  sx4 hi, lo;
#pragma unroll
  for (int e = 0; e < 4; ++e) {
    hi[e] = f2bf(v[e]);
    lo[e] = f2bf(v[e] - bf2f(hi[e]));
  }
  size_t o = ((size_t)(t * 32 + b)) * 256 + k;
  *(sx4*)(xhi + o) = hi;
  *(sx4*)(xlo + o) = lo;
}

// 3-layer pipelined persistent recurrence. 96 blocks x 256 thr.
// Block (l = bid>>5, p = bid&31) owns 16 output cols j0=p*16 of layer l.
// Tick t: layer l processes step s = t-l. Waves 0,1: input GEMM
// (x_t for l=0 [K=256], h_{l-1,s} for l>=1 [K=512]); waves 2,3: h2h GEMM
// (h_{l,s-1}, K=512). Weights (Wi and Wh slices, bf16 hi+lo) register-resident.
// All cross-block traffic via LLC: RELAXED agent atomics + sc0sc1 loads.
// hg layout per layer: [dbuf 2][hi/lo 2][32][512] bf16.
__global__ __launch_bounds__(256, 1) void rec3(
    const short* __restrict__ xth, const short* __restrict__ xtl,
    const float* __restrict__ Wi0, const float* __restrict__ bi0,
    const float* __restrict__ Wh0, const float* __restrict__ bh0,
    const float* __restrict__ Wi1, const float* __restrict__ bi1,
    const float* __restrict__ Wh1, const float* __restrict__ bh1,
    const float* __restrict__ Wi2, const float* __restrict__ bi2,
    const float* __restrict__ Wh2, const float* __restrict__ bh2,
    short* __restrict__ hg, int* flags, float* __restrict__ out)
{
  __shared__ __align__(16) float m_lds[4][32][52];  // [wave partial][batch][48 rows pad]
  __shared__ float bi_s[48], bh_s[48];
  const int tid = threadIdx.x;
  const int bid = blockIdx.x;
  const int l = bid >> 5, p = bid & 31, j0 = p * 16;
  const int w = tid >> 6, lane = tid & 63, lm = lane & 15, lk = lane >> 4;
  const bool inW = (w < 2);

  const float *Wi, *bi, *Wh, *bh;
  if (l == 0)      { Wi = Wi0; bi = bi0; Wh = Wh0; bh = bh0; }
  else if (l == 1) { Wi = Wi1; bi = bi1; Wh = Wh1; bh = bh1; }
  else             { Wi = Wi2; bi = bi2; Wh = Wh2; bh = bh2; }
  const int Kin = (l == 0) ? 256 : 512;
  const int ksn = inW ? (Kin >> 6) : 8;             // k-slices of 32 this wave
  const int kbase = inW ? w * (Kin >> 1) : (w - 2) * 256;
  const float* Wf = inW ? Wi : Wh;
  const int wstride = inW ? Kin : 512;

  // ---- weight slice -> register B-fragments, bf16 hi+lo ----
  bf8 bwh[3][8], bwl[3][8];
#pragma unroll
  for (int g = 0; g < 3; ++g) {
    const int grow = g * 512 + j0 + lm;
#pragma unroll
    for (int ks = 0; ks < 8; ++ks) if (ks < ksn) {
      const float* src = Wf + (size_t)grow * wstride + kbase + ks * 32 + lk * 8;
      fx4 f0 = *(const fx4*)(src);
      fx4 f1 = *(const fx4*)(src + 4);
      bf8 vh, vl;
#pragma unroll
      for (int e = 0; e < 4; ++e) {
        vh[e] = f2bf(f0[e]);     vl[e] = f2bf(f0[e] - bf2f(vh[e]));
        vh[4 + e] = f2bf(f1[e]); vl[4 + e] = f2bf(f1[e] - bf2f(vh[4 + e]));
      }
      bwh[g][ks] = vh; bwl[g][ks] = vl;
    }
  }
  if (tid < 48) {
    bi_s[tid] = bi[(tid >> 4) * 512 + j0 + (tid & 15)];
    bh_s[tid] = bh[(tid >> 4) * 512 + j0 + (tid & 15)];
  }

  short* hgl = hg + (size_t)l * 4 * HSZ;
  const short* hgp = hg + (size_t)(l - 1) * 4 * HSZ;   // only deref'd when l>=1
  {  // zero own dbuf1 (hi+lo) — h_{l,-1} = 0, read at s=0 (buf (s-1)&1 = 1)
    const int b = tid >> 3, zc = (tid & 7) * 2;
    __hip_atomic_store((int*)(hgl + (size_t)2 * HSZ + b * 512 + j0 + zc), 0,
                       __ATOMIC_RELAXED, __HIP_MEMORY_SCOPE_AGENT);
    __hip_atomic_store((int*)(hgl + (size_t)3 * HSZ + b * 512 + j0 + zc), 0,
                       __ATOMIC_RELAXED, __HIP_MEMORY_SCOPE_AGENT);
  }
  __syncthreads();   // drains stores before flag
  if (tid == 0)
    __hip_atomic_store(flags + bid * 32, 1, __ATOMIC_RELAXED, __HIP_MEMORY_SCOPE_AGENT);

  const int cb = tid >> 3, c2 = (tid & 7) * 2;   // cell phase: (batch, 2 cols)
  float hv0 = 0.f, hv1 = 0.f;                    // fp32 running h (own 2 cols)

  for (int t = 0; t < 514; ++t) {
    const int s = t - l;
    const bool active = ((unsigned)s < 512u);    // block-uniform

    ix4 rh[2][8], rl[2][8];
    // layer-0 input waves: x is static — prefetch before the barrier wait
    if (active && l == 0 && inW) {
      const short* x0h = xth + (size_t)(s * 32 + lm) * 256 + kbase + lk * 8;
      const short* x1h = x0h + 16 * 256;
      const short* x0l = xtl + (size_t)(s * 32 + lm) * 256 + kbase + lk * 8;
      const short* x1l = x0l + 16 * 256;
      LDP4(rh[0], x0h); LDP4(rh[1], x1h);
      LDP4(rl[0], x0l); LDP4(rl[1], x1l);
    }

    // global barrier: wait until every block finished tick t-1
    if (tid < NBLK) {
      while (__hip_atomic_load(flags + tid * 32, __ATOMIC_RELAXED,
                               __HIP_MEMORY_SCOPE_AGENT) < t + 1) {}
    }
    __syncthreads();

    if (active) {
      if (!(l == 0 && inW)) {   // h loads from LLC (ksn == 8 on all these paths)
        const short* basep = inW ? (hgp + (size_t)((s & 1) * 2) * HSZ)
                                 : (hgl + (size_t)(((s - 1) & 1) * 2) * HSZ);
        const short* s0h = basep + (size_t)lm * 512 + kbase + lk * 8;
        const short* s1h = s0h + 16 * 512;
        const short* s0l = s0h + HSZ;
        const short* s1l = s1h + HSZ;
        LDH8(rh[0], s0h); LDH8(rh[1], s1h);
        LDH8(rl[0], s0l); LDH8(rl[1], s1l);
      }
      asm volatile("s_waitcnt vmcnt(0)" ::: "memory");
      __builtin_amdgcn_sched_barrier(0);   // rule #18: keep MFMA below the wait

      fx4 acc[2][3];
#pragma unroll
      for (int mt = 0; mt < 2; ++mt)
#pragma unroll
        for (int g = 0; g < 3; ++g) acc[mt][g] = (fx4){0.f, 0.f, 0.f, 0.f};
#pragma unroll
      for (int ks = 0; ks < 8; ++ks) if (ks < ksn) {
#pragma unroll
        for (int mt = 0; mt < 2; ++mt) {
          bf8 ah = asbf8(rh[mt][ks]);
          bf8 al = asbf8(rl[mt][ks]);
#pragma unroll
          for (int g = 0; g < 3; ++g) {
            acc[mt][g] = __builtin_amdgcn_mfma_f32_16x16x32_bf16(ah, bwh[g][ks], acc[mt][g], 0, 0, 0);
            acc[mt][g] = __builtin_amdgcn_mfma_f32_16x16x32_bf16(al, bwh[g][ks], acc[mt][g], 0, 0, 0);
            acc[mt][g] = __builtin_amdgcn_mfma_f32_16x16x32_bf16(ah, bwl[g][ks], acc[mt][g], 0, 0, 0);
          }
        }
      }
#pragma unroll
      for (int mt = 0; mt < 2; ++mt)
#pragma unroll
        for (int g = 0; g < 3; ++g)
#pragma unroll
          for (int q = 0; q < 4; ++q)
            m_lds[w][mt * 16 + lk * 4 + q][g * 16 + lm] = acc[mt][g][q];
      __syncthreads();

      // cell phase: partials 0,1 = input GEMM (preact part), 2,3 = h2h
      float av[3][2], hh[3][2];
#pragma unroll
      for (int g = 0; g < 3; ++g)
#pragma unroll
        for (int e = 0; e < 2; ++e) {
          const int c = g * 16 + c2 + e;
          av[g][e] = m_lds[0][cb][c] + m_lds[1][cb][c] + bi_s[c];
          hh[g][e] = m_lds[2][cb][c] + m_lds[3][cb][c] + bh_s[c];
        }
      float hvv[2] = {hv0, hv1}, hn[2];
#pragma unroll
      for (int e = 0; e < 2; ++e) {
        float pr = av[0][e] + hh[0][e];
        float pz = av[1][e] + hh[1][e];
        float h2n = hh[2][e];
        float pn = av[2][e] + h2n;
        float sr = rcpf(1.f + __expf(-pr));  // sigmoid
        float rr = __expf(-__expf(-sr));     // Gumbel squash
        float sz = rcpf(1.f + __expf(-pz));
        float zz = __expf(-__expf(-sz));
        float na = pn + rr * h2n;
        float ex = __expf(2.f * na);         // tanh via exp
        float nn = 1.f - 2.f * rcpf(ex + 1.f);
        hn[e] = (1.f - zz) * nn + zz * hvv[e];
      }
      hv0 = hn[0]; hv1 = hn[1];
      short h0h = f2bf(hn[0]), h0l = f2bf(hn[0] - bf2f(h0h));
      short h1h = f2bf(hn[1]), h1l = f2bf(hn[1] - bf2f(h1h));
      int packh = (int)(unsigned short)h0h | ((int)(unsigned short)h1h << 16);
      int packl = (int)(unsigned short)h0l | ((int)(unsigned short)h1l << 16);

      short* hw = hgl + (size_t)((s & 1) * 2) * HSZ;
      __hip_atomic_store((int*)(hw + (size_t)cb * 512 + j0 + c2), packh,
                         __ATOMIC_RELAXED, __HIP_MEMORY_SCOPE_AGENT);
      __hip_atomic_store((int*)(hw + HSZ + (size_t)cb * 512 + j0 + c2), packl,
                         __ATOMIC_RELAXED, __HIP_MEMORY_SCOPE_AGENT);
      if (l == 2 && s == 511) {
        out[(size_t)cb * 512 + j0 + c2] = hn[0];
        out[(size_t)cb * 512 + j0 + c2 + 1] = hn[1];
      }
      __syncthreads();   // vmcnt(0) drain before barrier = release
    }
    if (tid == 0)
      __hip_atomic_store(flags + bid * 32, t + 2,
                         __ATOMIC_RELAXED, __HIP_MEMORY_SCOPE_AGENT);
  }
}

extern "C" void kernel_launch(void* const* d_in, const int* in_sizes, int n_in,
                              void* d_out, int out_size, void* d_ws, size_t ws_size,
                              hipStream_t stream) {
  const float* x   = (const float*)d_in[0];
  const float* Wi0 = (const float*)d_in[1];
  const float* bi0 = (const float*)d_in[2];
  const float* Wh0 = (const float*)d_in[3];
  const float* bh0 = (const float*)d_in[4];
  const float* Wi1 = (const float*)d_in[5];
  const float* bi1 = (const float*)d_in[6];
  const float* Wh1 = (const float*)d_in[7];
  const float* bh1 = (const float*)d_in[8];
  const float* Wi2 = (const float*)d_in[9];
  const float* bi2 = (const float*)d_in[10];
  const float* Wh2 = (const float*)d_in[11];
  const float* bh2 = (const float*)d_in[12];
  float* out = (float*)d_out;
  (void)in_sizes; (void)n_in; (void)out_size; (void)ws_size;

  char* ws = (char*)d_ws;
  size_t off = 0;
  auto alloc = [&](size_t b) { char* p = ws + off; off = (off + b + 255) & ~(size_t)255; return p; };
  short* xth   = (short*)alloc(16384ull * 256 * 2);   // 8.4 MB
  short* xtl   = (short*)alloc(16384ull * 256 * 2);
  short* hg    = (short*)alloc(3ull * 4 * HSZ * 2);   // 3 layers x [2][2][32][512]
  int*   flags = (int*)alloc(NBLK * 32 * 4);

  hipMemsetAsync(flags, 0, NBLK * 32 * 4, stream);
  hipLaunchKernelGGL(conv_x_k, dim3(4096), dim3(256), 0, stream, x, xth, xtl);
  hipLaunchKernelGGL(rec3, dim3(NBLK), dim3(256), 0, stream,
                     xth, xtl,
                     Wi0, bi0, Wh0, bh0,
                     Wi1, bi1, Wh1, bh1,
                     Wi2, bi2, Wh2, bh2,
                     hg, flags, out);
}

// Round 7
// 3296.188 us; speedup vs baseline: 4.0468x; 1.0132x over previous
//
#include <hip/hip_runtime.h>
#include <hip/hip_bf16.h>

typedef __attribute__((ext_vector_type(4))) float fx4;
typedef __attribute__((ext_vector_type(8))) short bf8;   // 8 x bf16
typedef __attribute__((ext_vector_type(4))) short sx4;   // 4 x bf16
typedef __attribute__((ext_vector_type(4))) int ix4;

#define NBLK 96          // 3 layers x 32 blocks
#define HSZ (32 * 512)   // one h plane (batch x hidden) in shorts

__device__ __forceinline__ short f2bf(float f) {
  __hip_bfloat16 h = __float2bfloat16(f);
  return *reinterpret_cast<short*>(&h);
}
__device__ __forceinline__ float bf2f(short s) {
  union { unsigned u; float f; } c; c.u = ((unsigned)(unsigned short)s) << 16; return c.f;
}
__device__ __forceinline__ float rcpf(float x) { return __builtin_amdgcn_rcpf(x); }
__device__ __forceinline__ bf8 asbf8(ix4 v) { union { ix4 i; bf8 b; } u; u.i = v; return u.b; }

// coherent (LLC) 16B load, bypasses local L1/L2 — for cross-XCD h broadcast
#define LDH(dst, p, OFF) \
  asm volatile("global_load_dwordx4 %0, %1, off offset:" OFF " sc0 sc1" \
               : "=v"(dst) : "v"(p) : "memory")
// plain cached 16B load (static data: x)
#define LDP(dst, p, OFF) \
  asm volatile("global_load_dwordx4 %0, %1, off offset:" OFF \
               : "=v"(dst) : "v"(p) : "memory")
#define LD8(OP, A, P) do { \
  OP(A[0], P, "0");   OP(A[1], P, "64");  OP(A[2], P, "128"); OP(A[3], P, "192"); \
  OP(A[4], P, "256"); OP(A[5], P, "320"); OP(A[6], P, "384"); OP(A[7], P, "448"); } while (0)

// x (B=32,T=512,D=256) fp32 -> xt (T,B,256) bf16 hi+lo (rows = t*32+b)
__global__ __launch_bounds__(256) void conv_x_k(const float* __restrict__ x,
                                                short* __restrict__ xhi, short* __restrict__ xlo) {
  int i = blockIdx.x * 256 + threadIdx.x;
  fx4 v = *(const fx4*)(x + (size_t)i * 4);
  int k = (i * 4) & 255;
  int row = (i * 4) >> 8;                            // b*512 + t
  int b = row >> 9, t = row & 511;
  sx4 hi, lo;
#pragma unroll
  for (int e = 0; e < 4; ++e) {
    hi[e] = f2bf(v[e]);
    lo[e] = f2bf(v[e] - bf2f(hi[e]));
  }
  size_t o = ((size_t)(t * 32 + b)) * 256 + k;
  *(sx4*)(xhi + o) = hi;
  *(sx4*)(xlo + o) = lo;
}

// Per-layer body, templated so every loop bound / stride is compile-time.
// Layer L, 32 blocks; block owns 16 output cols j0. Step s runs at tick t=s+L.
//
// FLAG PROTOCOL (flag[b] = completed step of block b, +3; init 2 = "completed
// step -1", i.e. initial h published). Block of layer L at step s waits:
//   prev-layer  flag >= s+3  (prev completed s   -> h_{L-1,s}   readable)
//   own-layer   flag >= s+2  (peers completed s-1-> h_{L,s-1}   readable)
//   next-layer  flag >= s    (next completed s-3 -> buf s%3, holding
//                             h_{L,s-3}, fully consumed; safe to overwrite)
// hg per layer: [buf 3][hi/lo 2][32][512] bf16; step s -> buf s%3.
template<int L>
__device__ __forceinline__ void rec3_body(
    float (*m_lds)[32][52], float* bias_s,
    const short* __restrict__ xth, const short* __restrict__ xtl,
    const float* __restrict__ Wi, const float* __restrict__ bi,
    const float* __restrict__ Wh, const float* __restrict__ bh,
    short* __restrict__ hg, int* flags, float* __restrict__ out)
{
  const int tid = threadIdx.x;
  const int bid = blockIdx.x;
  const int j0 = (bid & 31) * 16;
  const int w = tid >> 6, lane = tid & 63, lm = lane & 15, lk = lane >> 4;
  const bool inW = (w < 2);
  constexpr int KIN = (L == 0) ? 256 : 512;

  short* hgl = hg + (size_t)L * 6 * HSZ;
  const short* hgp = (L > 0) ? (hg + (size_t)(L - 1) * 6 * HSZ) : hg;

  // L==0 input waves: M-split (wave w covers batches w*16..w*16+15), full K=256.
  // All other waves: K-split (256 each), both 16-batch M-tiles.
  const int kbase = inW ? ((L == 0) ? 0 : w * 256) : (w - 2) * 256;
  const float* Wf = inW ? Wi : Wh;
  const int wstr = inW ? KIN : 512;

  // ---- weight slice -> register B-fragments, bf16 hi+lo (static 3x8) ----
  bf8 bwh[3][8], bwl[3][8];
#pragma unroll
  for (int g = 0; g < 3; ++g) {
    const int grow = g * 512 + j0 + lm;
#pragma unroll
    for (int ks = 0; ks < 8; ++ks) {
      const float* src = Wf + (size_t)grow * wstr + kbase + ks * 32 + lk * 8;
      fx4 f0 = *(const fx4*)(src);
      fx4 f1 = *(const fx4*)(src + 4);
      bf8 vh, vl;
#pragma unroll
      for (int e = 0; e < 4; ++e) {
        vh[e] = f2bf(f0[e]);     vl[e] = f2bf(f0[e] - bf2f(vh[e]));
        vh[4 + e] = f2bf(f1[e]); vl[4 + e] = f2bf(f1[e] - bf2f(vh[4 + e]));
      }
      bwh[g][ks] = vh; bwl[g][ks] = vl;
    }
  }
  if (tid < 48) bias_s[tid] = bi[(tid >> 4) * 512 + j0 + (tid & 15)];
  else if (tid < 96) {
    const int u = tid - 48;
    bias_s[48 + u] = bh[(u >> 4) * 512 + j0 + (u & 15)];
  }
  {  // zero own buf 2 (hi+lo): h_{L,-1} = 0, read at s=0 (bufr = (0-1)%3 = 2)
    const int b = tid >> 3, zc = (tid & 7) * 2;
    __hip_atomic_store((int*)(hgl + (size_t)4 * HSZ + b * 512 + j0 + zc), 0,
                       __ATOMIC_RELAXED, __HIP_MEMORY_SCOPE_AGENT);
    __hip_atomic_store((int*)(hgl + (size_t)5 * HSZ + b * 512 + j0 + zc), 0,
                       __ATOMIC_RELAXED, __HIP_MEMORY_SCOPE_AGENT);
  }
  __syncthreads();   // drain stores before flag (release)
  if (tid == 0)
    __hip_atomic_store(flags + bid * 32, 2, __ATOMIC_RELAXED, __HIP_MEMORY_SCOPE_AGENT);

  constexpr int FBASE = (L == 0) ? 0 : (L - 1) * 32;
  constexpr int FCNT  = (L == 1) ? 96 : 64;
  const int cb = tid >> 3, c2 = (tid & 7) * 2;   // cell phase: (batch, 2 cols)
  float hv0 = 0.f, hv1 = 0.f;
  int bufw = 0;                                   // s % 3

  for (int s = 0; s < 512; ++s) {
    ix4 rh[2][8], rl[2][8];
    if (L == 0 && inW) {   // x is static — prefetch before the wait
      const short* xh = xth + (size_t)(s * 32 + w * 16 + lm) * 256 + lk * 8;
      const short* xl = xtl + (size_t)(s * 32 + w * 16 + lm) * 256 + lk * 8;
      LD8(LDP, rh[0], xh);
      LD8(LDP, rl[0], xl);
    }

    if (tid < FCNT) {
      const int f = FBASE + tid;
      const int fl = f >> 5;
      // prev: s+3, own peers: s+2, next: s  (see protocol comment above)
      const int thr = (fl < L) ? (s + 3) : ((fl == L) ? (s + 2) : s);
      while (__hip_atomic_load(flags + f * 32, __ATOMIC_RELAXED,
                               __HIP_MEMORY_SCOPE_AGENT) < thr)
        __builtin_amdgcn_s_sleep(1);
    }
    __syncthreads();

    const int bufr = (bufw == 0) ? 2 : bufw - 1;   // (s-1) % 3
    if (!(L == 0 && inW)) {
      const short* basep = inW ? (hgp + (size_t)(bufw * 2) * HSZ)
                               : (hgl + (size_t)(bufr * 2) * HSZ);
      const short* s0h = basep + (size_t)lm * 512 + kbase + lk * 8;
      const short* s1h = s0h + 16 * 512;
      const short* s0l = s0h + HSZ;
      const short* s1l = s1h + HSZ;
      LD8(LDH, rh[0], s0h); LD8(LDH, rh[1], s1h);
      LD8(LDH, rl[0], s0l); LD8(LDH, rl[1], s1l);
    }
    asm volatile("s_waitcnt vmcnt(0)" ::: "memory");
    __builtin_amdgcn_sched_barrier(0);   // rule #18

    fx4 acc[2][3];
#pragma unroll
    for (int mt = 0; mt < 2; ++mt)
#pragma unroll
      for (int g = 0; g < 3; ++g) acc[mt][g] = (fx4){0.f, 0.f, 0.f, 0.f};

    if (L == 0 && inW) {
#pragma unroll
      for (int ks = 0; ks < 8; ++ks) {
        bf8 ah = asbf8(rh[0][ks]);
        bf8 al = asbf8(rl[0][ks]);
#pragma unroll
        for (int g = 0; g < 3; ++g) {
          acc[0][g] = __builtin_amdgcn_mfma_f32_16x16x32_bf16(ah, bwh[g][ks], acc[0][g], 0, 0, 0);
          acc[0][g] = __builtin_amdgcn_mfma_f32_16x16x32_bf16(al, bwh[g][ks], acc[0][g], 0, 0, 0);
          acc[0][g] = __builtin_amdgcn_mfma_f32_16x16x32_bf16(ah, bwl[g][ks], acc[0][g], 0, 0, 0);
        }
      }
    } else {
#pragma unroll
      for (int ks = 0; ks < 8; ++ks) {
#pragma unroll
        for (int mt = 0; mt < 2; ++mt) {
          bf8 ah = asbf8(rh[mt][ks]);
          bf8 al = asbf8(rl[mt][ks]);
#pragma unroll
          for (int g = 0; g < 3; ++g) {
            acc[mt][g] = __builtin_amdgcn_mfma_f32_16x16x32_bf16(ah, bwh[g][ks], acc[mt][g], 0, 0, 0);
            acc[mt][g] = __builtin_amdgcn_mfma_f32_16x16x32_bf16(al, bwh[g][ks], acc[mt][g], 0, 0, 0);
            acc[mt][g] = __builtin_amdgcn_mfma_f32_16x16x32_bf16(ah, bwl[g][ks], acc[mt][g], 0, 0, 0);
          }
        }
      }
    }

    if (L == 0 && inW) {   // wave w -> rows w*16.. of partial plane 0
#pragma unroll
      for (int g = 0; g < 3; ++g)
#pragma unroll
        for (int q = 0; q < 4; ++q)
          m_lds[0][w * 16 + lk * 4 + q][g * 16 + lm] = acc[0][g][q];
    } else {
#pragma unroll
      for (int mt = 0; mt < 2; ++mt)
#pragma unroll
        for (int g = 0; g < 3; ++g)
#pragma unroll
          for (int q = 0; q < 4; ++q)
            m_lds[w][mt * 16 + lk * 4 + q][g * 16 + lm] = acc[mt][g][q];
    }
    __syncthreads();

    // cell: planes 0(,1) = input partial(s), 2,3 = h2h K-halves
    float av[3][2], hh[3][2];
#pragma unroll
    for (int g = 0; g < 3; ++g)
#pragma unroll
      for (int e = 0; e < 2; ++e) {
        const int c = g * 16 + c2 + e;
        float ain = m_lds[0][cb][c];
        if (L > 0) ain += m_lds[1][cb][c];
        av[g][e] = ain + bias_s[c];
        hh[g][e] = m_lds[2][cb][c] + m_lds[3][cb][c] + bias_s[48 + c];
      }
    float hvv[2] = {hv0, hv1}, hn[2];
#pragma unroll
    for (int e = 0; e < 2; ++e) {
      float pr = av[0][e] + hh[0][e];
      float pz = av[1][e] + hh[1][e];
      float h2n = hh[2][e];
      float pn = av[2][e] + h2n;
      float sr = rcpf(1.f + __expf(-pr));  // sigmoid
      float rr = __expf(-__expf(-sr));     // Gumbel squash
      float sz = rcpf(1.f + __expf(-pz));
      float zz = __expf(-__expf(-sz));
      float na = pn + rr * h2n;
      float ex = __expf(2.f * na);         // tanh via exp
      float nn = 1.f - 2.f * rcpf(ex + 1.f);
      hn[e] = (1.f - zz) * nn + zz * hvv[e];
    }
    hv0 = hn[0]; hv1 = hn[1];
    short h0h = f2bf(hn[0]), h0l = f2bf(hn[0] - bf2f(h0h));
    short h1h = f2bf(hn[1]), h1l = f2bf(hn[1] - bf2f(h1h));
    int packh = (int)(unsigned short)h0h | ((int)(unsigned short)h1h << 16);
    int packl = (int)(unsigned short)h0l | ((int)(unsigned short)h1l << 16);

    short* hw = hgl + (size_t)(bufw * 2) * HSZ;
    __hip_atomic_store((int*)(hw + (size_t)cb * 512 + j0 + c2), packh,
                       __ATOMIC_RELAXED, __HIP_MEMORY_SCOPE_AGENT);
    __hip_atomic_store((int*)(hw + HSZ + (size_t)cb * 512 + j0 + c2), packl,
                       __ATOMIC_RELAXED, __HIP_MEMORY_SCOPE_AGENT);
    if (L == 2 && s == 511) {
      out[(size_t)cb * 512 + j0 + c2] = hn[0];
      out[(size_t)cb * 512 + j0 + c2 + 1] = hn[1];
    }
    __syncthreads();   // vmcnt(0) drain in every wave before the flag = release
    if (tid == 0)
      __hip_atomic_store(flags + bid * 32, s + 3,
                         __ATOMIC_RELAXED, __HIP_MEMORY_SCOPE_AGENT);

    bufw = (bufw == 2) ? 0 : bufw + 1;
  }
}

__global__ __launch_bounds__(256, 1) void rec3(
    const short* __restrict__ xth, const short* __restrict__ xtl,
    const float* __restrict__ Wi0, const float* __restrict__ bi0,
    const float* __restrict__ Wh0, const float* __restrict__ bh0,
    const float* __restrict__ Wi1, const float* __restrict__ bi1,
    const float* __restrict__ Wh1, const float* __restrict__ bh1,
    const float* __restrict__ Wi2, const float* __restrict__ bi2,
    const float* __restrict__ Wh2, const float* __restrict__ bh2,
    short* __restrict__ hg, int* flags, float* __restrict__ out)
{
  __shared__ __align__(16) float m_lds[4][32][52];
  __shared__ float bias_s[96];
  const int l = blockIdx.x >> 5;
  if (l == 0)
    rec3_body<0>(m_lds, bias_s, xth, xtl, Wi0, bi0, Wh0, bh0, hg, flags, out);
  else if (l == 1)
    rec3_body<1>(m_lds, bias_s, nullptr, nullptr, Wi1, bi1, Wh1, bh1, hg, flags, out);
  else
    rec3_body<2>(m_lds, bias_s, nullptr, nullptr, Wi2, bi2, Wh2, bh2, hg, flags, out);
}

extern "C" void kernel_launch(void* const* d_in, const int* in_sizes, int n_in,
                              void* d_out, int out_size, void* d_ws, size_t ws_size,
                              hipStream_t stream) {
  const float* x   = (const float*)d_in[0];
  const float* Wi0 = (const float*)d_in[1];
  const float* bi0 = (const float*)d_in[2];
  const float* Wh0 = (const float*)d_in[3];
  const float* bh0 = (const float*)d_in[4];
  const float* Wi1 = (const float*)d_in[5];
  const float* bi1 = (const float*)d_in[6];
  const float* Wh1 = (const float*)d_in[7];
  const float* bh1 = (const float*)d_in[8];
  const float* Wi2 = (const float*)d_in[9];
  const float* bi2 = (const float*)d_in[10];
  const float* Wh2 = (const float*)d_in[11];
  const float* bh2 = (const float*)d_in[12];
  float* out = (float*)d_out;
  (void)in_sizes; (void)n_in; (void)out_size; (void)ws_size;

  char* ws = (char*)d_ws;
  size_t off = 0;
  auto alloc = [&](size_t b) { char* p = ws + off; off = (off + b + 255) & ~(size_t)255; return p; };
  short* xth   = (short*)alloc(16384ull * 256 * 2);   // 8.4 MB
  short* xtl   = (short*)alloc(16384ull * 256 * 2);
  short* hg    = (short*)alloc(3ull * 6 * HSZ * 2);   // 3 layers x [3buf][hi/lo][32][512]
  int*   flags = (int*)alloc(NBLK * 32 * 4);

  hipMemsetAsync(flags, 0, NBLK * 32 * 4, stream);
  hipLaunchKernelGGL(conv_x_k, dim3(4096), dim3(256), 0, stream, x, xth, xtl);
  hipLaunchKernelGGL(rec3, dim3(NBLK), dim3(256), 0, stream,
                     xth, xtl,
                     Wi0, bi0, Wh0, bh0,
                     Wi1, bi1, Wh1, bh1,
                     Wi2, bi2, Wh2, bh2,
                     hg, flags, out);
}